// Round 5
// baseline (24.583 us; speedup 1.0000x reference)
//
#include <hip/hip_runtime.h>
#include <cfloat>

#define NS 7
#define NC 256
#define NH 64
#define NW 64
#define NR 128
#define RG 16            // rois per block
#define PW 68            // padded row stride in floats; 68*4=272B, 272%16==0 -> quads 16B-aligned

// Block = (channel, roi-group of 16). Grid = 256*8 = 2048 = 8 blocks/CU resident.
// Plane staged in LDS; window max read as aligned float4 quads (ds_read_b128),
// edge masks applied once per quad-column.
__global__ __launch_bounds__(256, 8) void roi_pool_kernel(
    const float* __restrict__ f,
    const int* __restrict__ rois,
    float* __restrict__ out)
{
    __shared__ float plane[NH][PW];                       // 17,408 B
    __shared__ int hs_[RG][NS], he_[RG][NS];
    __shared__ int ws_[RG][NS], we_[RG][NS];              // 1,792 B

    const int tid = threadIdx.x;
    const int c   = blockIdx.x >> 3;  // channel
    const int g   = blockIdx.x & 7;   // roi group

    // Stage 64x64 plane: 1024 float4s, 4 per thread, independent issues.
    {
        const float4* src = (const float4*)(f + (size_t)c * (NH * NW));
        #pragma unroll
        for (int k = 0; k < 4; ++k) {
            int q  = tid + k * 256;        // float4 index 0..1023
            int h  = q >> 4;               // 16 quads per 64-wide row
            int w4 = (q & 15) * 4;
            float4 v = src[q];
            *(float4*)&plane[h][w4] = v;
        }
    }

    // Per-roi adaptive bin boundaries (PyTorch semantics), once per block.
    if (tid < RG) {
        int r  = g * RG + tid;
        int x1 = rois[4*r+0], y1 = rois[4*r+1];
        int x2 = rois[4*r+2], y2 = rois[4*r+3];
        int Lh = x2 - x1 + 1, Lw = y2 - y1 + 1;
        #pragma unroll
        for (int i = 0; i < NS; ++i) {
            hs_[tid][i] = x1 + (i * Lh) / NS;
            he_[tid][i] = x1 + ((i + 1) * Lh + NS - 1) / NS;
            ws_[tid][i] = y1 + (i * Lw) / NS;
            we_[tid][i] = y1 + ((i + 1) * Lw + NS - 1) / NS;
        }
    }

    __syncthreads();

    // Outputs: RG*49 = 784 per block, ~3 per thread.
    for (int o = tid; o < RG * NS * NS; o += 256) {
        int lr  = o / (NS * NS);
        int bin = o - lr * (NS * NS);
        int i   = bin / NS;
        int j   = bin - i * NS;

        int h0 = hs_[lr][i], h1 = he_[lr][i];
        int w0 = ws_[lr][j], w1 = we_[lr][j];

        int q0 = w0 >> 2;
        int q1 = (w1 + 3) >> 2;
        unsigned span = (unsigned)(w1 - w0);

        float m = -FLT_MAX;
        for (int q = q0; q < q1; ++q) {
            // column max over rows for this aligned quad (b128 reads)
            float4 col = make_float4(-FLT_MAX, -FLT_MAX, -FLT_MAX, -FLT_MAX);
            for (int h = h0; h < h1; ++h) {
                float4 v = *(const float4*)&plane[h][q * 4];
                col.x = fmaxf(col.x, v.x);
                col.y = fmaxf(col.y, v.y);
                col.z = fmaxf(col.z, v.z);
                col.w = fmaxf(col.w, v.w);
            }
            // apply w-edge mask once per quad-column
            int wb = q * 4;
            m = fmaxf(m, ((unsigned)(wb + 0 - w0) < span) ? col.x : -FLT_MAX);
            m = fmaxf(m, ((unsigned)(wb + 1 - w0) < span) ? col.y : -FLT_MAX);
            m = fmaxf(m, ((unsigned)(wb + 2 - w0) < span) ? col.z : -FLT_MAX);
            m = fmaxf(m, ((unsigned)(wb + 3 - w0) < span) ? col.w : -FLT_MAX);
        }

        int r = g * RG + lr;
        out[((size_t)(r * NC + c)) * (NS * NS) + bin] = m;
    }
}

extern "C" void kernel_launch(void* const* d_in, const int* in_sizes, int n_in,
                              void* d_out, int out_size, void* d_ws, size_t ws_size,
                              hipStream_t stream)
{
    const float* feature_map = (const float*)d_in[0];
    const int*   rois        = (const int*)d_in[1];
    float*       out         = (float*)d_out;

    const int grid  = NC * (NR / RG);  // 256 * 8 = 2048 blocks
    const int block = 256;

    roi_pool_kernel<<<grid, block, 0, stream>>>(feature_map, rois, out);
}